// Round 4
// baseline (112.987 us; speedup 1.0000x reference)
//
#include <hip/hip_runtime.h>
#include <hip/hip_bf16.h>
#include <math.h>

#define BB 2
#define NN 1024
#define HH 4
#define F_IN 128
#define HID 32
#define TJ 64
#define NT (NN/TJ)     // 16 j-tiles, one u64 mask word each

typedef unsigned int u32;
typedef unsigned long long u64;

// ---- workspace layout (bytes) ----
#define WS_XBF  0              // bf16 x pre-scaled by 0.4: B*H*N*HID*2 = 524288
#define WS_D6   524288         // f32 B*H*N = 32768  (0.6 * Wa.x_true)
#define WS_BITS 557056         // u64 B*N*NT = 262144

// ---------------- Kernel 1: proj (x=feat@W), d6, bf16(0.4x) write, adj bit-pack
__global__ __launch_bounds__(128) void gat_proj_kernel(const float* __restrict__ feat,
        const float* __restrict__ W, const float* __restrict__ Wa, const int* __restrict__ adj,
        __hip_bfloat16* __restrict__ xbf, float* __restrict__ d6, u64* __restrict__ bits) {
    const int RPB = 2;
    int blk = blockIdx.x;              // 0 .. BB*NN/2-1
    int b  = blk / (NN / RPB);
    int n0 = (blk % (NN / RPB)) * RPB;
    int t  = threadIdx.x;              // 0..127 -> output column h*32+k

    __shared__ float fs[RPB][F_IN];
    fs[0][t] = feat[((size_t)(b*NN + n0    ))*F_IN + t];
    fs[1][t] = feat[((size_t)(b*NN + n0 + 1))*F_IN + t];
    __syncthreads();

    float a0 = 0.f, a1 = 0.f;
    for (int f = 0; f < F_IN; ++f) {
        float w = W[f*(HH*HID) + t];
        a0 = fmaf(fs[0][f], w, a0);
        a1 = fmaf(fs[1][f], w, a1);
    }
    int h = t >> 5, k = t & 31;
    int bh = b*HH + h;
    xbf[((size_t)bh*NN + n0    )*HID + k] = __float2bfloat16(0.4f*a0);
    xbf[((size_t)bh*NN + n0 + 1)*HID + k] = __float2bfloat16(0.4f*a1);
    float w_t = Wa[t];
    float p0 = a0*w_t, p1 = a1*w_t;
#pragma unroll
    for (int off = 16; off >= 1; off >>= 1) {
        p0 += __shfl_xor(p0, off, 32);
        p1 += __shfl_xor(p1, off, 32);
    }
    if (k == 0) {
        d6[(size_t)bh*NN + n0    ] = 0.6f*p0;
        d6[(size_t)bh*NN + n0 + 1] = 0.6f*p1;
    }
    // adjacency bit-pack for our 2 rows (h-independent, done once per (b,row) pair per h? no:
    // this block is unique per (b,n0) since grid is b x n-rows; all 128 threads participate)
#pragma unroll
    for (int r = 0; r < RPB; ++r) {
        const int* arow = adj + ((size_t)(b*NN + n0 + r))*NN;
        u64* brow = bits + ((size_t)(b*NN + n0 + r))*NT;
#pragma unroll
        for (int c0 = 0; c0 < NN; c0 += 128) {
            u64 m = __ballot(arow[c0 + t] > 0);
            if ((t & 63) == 0) brow[(c0 + t) >> 6] = m;
        }
    }
}

// ---------------- Kernel 2: fused attention. 256 thr (4 waves), 1 query row per wave.
// lane = j within tile; xi/Wa/ci in SGPRs; bf16 swizzled LDS tiles; fixed m=0 softmax.
#define UNPK(U, O) \
    xj[O+0]=__uint_as_float((U).x<<16); xj[O+1]=__uint_as_float((U).x&0xffff0000u); \
    xj[O+2]=__uint_as_float((U).y<<16); xj[O+3]=__uint_as_float((U).y&0xffff0000u); \
    xj[O+4]=__uint_as_float((U).z<<16); xj[O+5]=__uint_as_float((U).z&0xffff0000u); \
    xj[O+6]=__uint_as_float((U).w<<16); xj[O+7]=__uint_as_float((U).w&0xffff0000u);

#define TILE(T, P) { \
    *(uint4*)&xs[P][wrofs] = pre; \
    __syncthreads(); \
    if ((T) + 1 < NT) pre = gsrc[((T)+1)*256 + tid]; \
    u64 mbits = brow[T]; \
    uint4 Aq = *(const uint4*)&xs[P][rd0]; \
    uint4 Bq = *(const uint4*)&xs[P][rd1]; \
    uint4 Cq = *(const uint4*)&xs[P][rd2]; \
    uint4 Dq = *(const uint4*)&xs[P][rd3]; \
    float dj = dbh[(T)*TJ + l]; \
    float xj[32]; \
    UNPK(Aq, 0) UNPK(Bq, 8) UNPK(Cq, 16) UNPK(Dq, 24) \
    float s0=0.f,s1=0.f,s2=0.f,s3=0.f; \
    _Pragma("unroll") \
    for (int k = 0; k < 32; k += 4) { \
        float v0 = xif[k+0]+xj[k+0]; s0 = fmaf(waf[k+0], fabsf(v0), s0); \
        float v1 = xif[k+1]+xj[k+1]; s1 = fmaf(waf[k+1], fabsf(v1), s1); \
        float v2 = xif[k+2]+xj[k+2]; s2 = fmaf(waf[k+2], fabsf(v2), s2); \
        float v3 = xif[k+3]+xj[k+3]; s3 = fmaf(waf[k+3], fabsf(v3), s3); \
    } \
    float ee = (ci + dj) + ((s0+s1)+(s2+s3)); \
    float pe = __expf(ee); \
    float pp = ((mbits >> l) & 1ull) ? pe : 0.f; \
    lsum += pp; \
    _Pragma("unroll") \
    for (int k = 0; k < 32; ++k) acc[k] = fmaf(pp, xj[k], acc[k]); \
}

__global__ __launch_bounds__(256, 6) void gat_attn_kernel(const __hip_bfloat16* __restrict__ xbf,
        const float* __restrict__ d6, const u64* __restrict__ bits,
        const float* __restrict__ Wa, float* __restrict__ out) {
    const int tid = threadIdx.x;
    const int w = tid >> 6, l = tid & 63;
    const int blk = blockIdx.x;                  // 0..2047
    const int bh = blk >> 8;                     // 256 blocks per (b,h)
    const int i0 = (blk & 255) << 2;             // 4 rows per block
    const int h = bh & (HH - 1), b = bh >> 2;
    const int i = i0 + w;                        // this wave's query row

    const u32* xw = (const u32*)xbf + (size_t)bh*(NN*HID/2);   // dword view, 16 dw/row
    const float* dbh = d6 + (size_t)bh*NN;
    const u64* brow = bits + ((size_t)b*NN + i)*NT;

    // wave-uniform constants -> SGPRs via readfirstlane
    float xif[32], waf[32];
    const u32* xiu = xw + i*16;
#pragma unroll
    for (int q = 0; q < 16; ++q) {
        u32 d = __builtin_amdgcn_readfirstlane(xiu[q]);
        xif[2*q]   = __uint_as_float(d << 16);
        xif[2*q+1] = __uint_as_float(d & 0xffff0000u);
    }
#pragma unroll
    for (int k = 0; k < 32; ++k)
        waf[k] = __uint_as_float(__builtin_amdgcn_readfirstlane(__float_as_uint(Wa[h*HID + k])));
    float ci = __uint_as_float(__builtin_amdgcn_readfirstlane(__float_as_uint(dbh[i])));

    __shared__ u32 xs[2][64*16];          // 2 x 4 KB bf16 tiles, quad-swizzled
    __shared__ float scr[4][32*33];       // per-wave epilogue transpose (16.9 KB)

    float acc[32];
#pragma unroll
    for (int k = 0; k < 32; ++k) acc[k] = 0.f;
    float lsum = 0.f;

    // stage-writer: thread t -> row t>>2, quad t&3, swizzled quad = q ^ ((row>>1)&3)
    const int srow = tid >> 2, sq = tid & 3;
    const int wrofs = srow*16 + ((sq ^ ((srow >> 1) & 3)) << 2);
    // reader: lane l reads row l, logical quad q at physical q ^ ((l>>1)&3)
    const int rq = (l >> 1) & 3;
    const int rb = l*16;
    const int rd0 = rb + ((0 ^ rq) << 2);
    const int rd1 = rb + ((1 ^ rq) << 2);
    const int rd2 = rb + ((2 ^ rq) << 2);
    const int rd3 = rb + ((3 ^ rq) << 2);

    const uint4* gsrc = (const uint4*)xw;   // tile t: 256 x 16B, coalesced
    uint4 pre = gsrc[tid];                  // prefetch tile 0

    for (int t2 = 0; t2 < NT; t2 += 2) {
        TILE(t2,     0)
        TILE(t2 + 1, 1)
    }

    // ---- epilogue: fold upper 32 lanes, denominator butterfly, per-wave LDS transpose
#pragma unroll
    for (int k = 0; k < 32; ++k) acc[k] += __shfl_xor(acc[k], 32, 64);
#pragma unroll
    for (int off = 32; off >= 1; off >>= 1) lsum += __shfl_xor(lsum, off, 64);

    float* sw = scr[w];                    // wave-private: no barrier needed
    if (l < 32) {
#pragma unroll
        for (int k = 0; k < 32; ++k) sw[k*33 + l] = acc[k];
    }
    if (l < 32) {
        float res = 0.f;
#pragma unroll
        for (int m = 0; m < 32; ++m) res += sw[l*33 + m];
        // x was pre-scaled by 0.4 -> undo with 2.5
        out[((size_t)(b*NN + i))*(HH*HID) + h*HID + l] = res * (2.5f / lsum);
    }
}

extern "C" void kernel_launch(void* const* d_in, const int* in_sizes, int n_in,
                              void* d_out, int out_size, void* d_ws, size_t ws_size,
                              hipStream_t stream) {
    const float* node_feat = (const float*)d_in[0];
    const int*   adj_mtx   = (const int*)d_in[1];
    const float* W         = (const float*)d_in[2];
    const float* Wa        = (const float*)d_in[3];
    float* out = (float*)d_out;

    char* ws = (char*)d_ws;
    __hip_bfloat16* xbf  = (__hip_bfloat16*)(ws + WS_XBF);
    float*          d6_w = (float*)(ws + WS_D6);
    u64*            bits = (u64*)(ws + WS_BITS);

    hipLaunchKernelGGL(gat_proj_kernel, dim3(BB*NN/2), dim3(128), 0, stream,
                       node_feat, W, Wa, adj_mtx, xbf, d6_w, bits);
    hipLaunchKernelGGL(gat_attn_kernel, dim3(BB*HH*NN/4), dim3(256), 0, stream,
                       xbf, d6_w, bits, Wa, out);
}

// Round 6
// 51.433 us; speedup vs baseline: 2.1968x; 2.1968x over previous
//
#include <hip/hip_runtime.h>
#include <math.h>

#define BB 2
#define NN 1024
#define HH 4
#define F_IN 128
#define HID 32
#define TJ 64
#define NT (NN/TJ)     // 16 j-tiles, one u64 mask word each

typedef unsigned long long u64;

// ---- workspace layout (bytes) ----
#define WS_X    0              // f32 x: B*H*N*HID*4 = 1048576
#define WS_D6   1048576        // f32 B*H*N = 32768  (0.6 * Wa.x per node)
#define WS_BITS 1081344        // u64 B*N*NT = 262144

// ---------------- Kernel 1: proj (x=feat@W) + d6 + adjacency bit-pack
__global__ __launch_bounds__(128) void gat_proj_kernel(const float* __restrict__ feat,
        const float* __restrict__ W, const float* __restrict__ Wa, const int* __restrict__ adj,
        float* __restrict__ xout, float* __restrict__ d6, u64* __restrict__ bits) {
    const int RPB = 2;
    int blk = blockIdx.x;              // 0 .. BB*NN/2-1
    int b  = blk / (NN / RPB);
    int n0 = (blk % (NN / RPB)) * RPB;
    int t  = threadIdx.x;              // 0..127 -> output column h*32+k

    __shared__ float fs[RPB][F_IN];
    fs[0][t] = feat[((size_t)(b*NN + n0    ))*F_IN + t];
    fs[1][t] = feat[((size_t)(b*NN + n0 + 1))*F_IN + t];
    __syncthreads();

    float a0 = 0.f, a1 = 0.f;
    for (int f = 0; f < F_IN; ++f) {
        float w = W[f*(HH*HID) + t];
        a0 = fmaf(fs[0][f], w, a0);
        a1 = fmaf(fs[1][f], w, a1);
    }
    int h = t >> 5, k = t & 31;
    int bh = b*HH + h;
    xout[((size_t)bh*NN + n0    )*HID + k] = a0;
    xout[((size_t)bh*NN + n0 + 1)*HID + k] = a1;
    float w_t = Wa[t];
    float p0 = a0*w_t, p1 = a1*w_t;
#pragma unroll
    for (int off = 16; off >= 1; off >>= 1) {
        p0 += __shfl_xor(p0, off, 32);
        p1 += __shfl_xor(p1, off, 32);
    }
    if (k == 0) {
        d6[(size_t)bh*NN + n0    ] = 0.6f*p0;
        d6[(size_t)bh*NN + n0 + 1] = 0.6f*p1;
    }
    // adjacency bit-pack for this block's 2 rows
#pragma unroll
    for (int r = 0; r < RPB; ++r) {
        const int* arow = adj + ((size_t)(b*NN + n0 + r))*NN;
        u64* brow = bits + ((size_t)(b*NN + n0 + r))*NT;
#pragma unroll
        for (int c0 = 0; c0 < NN; c0 += 128) {
            u64 m = __ballot(arow[c0 + t] > 0);
            if ((t & 63) == 0) brow[(c0 + t) >> 6] = m;
        }
    }
}

// ---------------- Kernel 2: fused attention. 256 thr (4 waves), 2 query rows per wave.
// lane = j within the 64-row LDS tile; fixed m=0 softmax; per-lane partial acc;
// lane-fold + per-wave LDS transpose-reduce at the end (reusing the tile buffer).
__global__ __launch_bounds__(256) void gat_attn2_kernel(const float* __restrict__ x,
                                                        const float* __restrict__ d6,
                                                        const u64* __restrict__ bits,
                                                        const float* __restrict__ Wa,
                                                        float* __restrict__ out) {
    const int tid = threadIdx.x;
    const int w = __builtin_amdgcn_readfirstlane(tid >> 6);   // wave id 0..3
    const int l = tid & 63;
    const int blk = blockIdx.x;                // 0..1023
    const int bh = blk >> 7;                   // 128 blocks per (b,h)
    const int i0 = (blk & 127) << 3;           // 8 rows per block
    const int h = bh & (HH - 1), b = bh >> 2;
    const int iA = i0 + 2*w, iB = iA + 1;

    const float* xbh = x  + (size_t)bh * NN * HID;
    const float* dbh = d6 + (size_t)bh * NN;
    const u64* brA = bits + ((size_t)b*NN + iA) * NT;
    const u64* brB = bits + ((size_t)b*NN + iB) * NT;

    float xiA[HID], xiB[HID], wa4[HID];
#pragma unroll
    for (int k = 0; k < HID; ++k) {
        xiA[k] = xbh[(size_t)iA*HID + k];
        xiB[k] = xbh[(size_t)iB*HID + k];
        wa4[k] = 0.4f * Wa[h*HID + k];
    }
    float ciA = dbh[iA], ciB = dbh[iB];

    __shared__ float xs[2][TJ][36];     // 18.4 KB, pad 36 -> conflict-free b128
    __shared__ float xd[2][TJ];         // 0.5 KB

    float accA[HID], accB[HID];
#pragma unroll
    for (int k = 0; k < HID; ++k) { accA[k] = 0.f; accB[k] = 0.f; }
    float lsA = 0.f, lsB = 0.f;

    // staging: tile = 64 rows x 32 floats = 512 float4; 256 threads x 2
    const int r0 = tid >> 3,         q0 = (tid & 7) << 2;         // element tid
    const int r1 = (tid + 256) >> 3, q1 = ((tid + 256) & 7) << 2; // element tid+256
    const float4* gsrc = (const float4*)xbh;
    float4 pre0 = gsrc[tid];
    float4 pre1 = gsrc[tid + 256];
    float pred = (tid < TJ) ? dbh[tid] : 0.f;

    for (int t = 0; t < NT; ++t) {
        const int bc = t & 1;
        *(float4*)&xs[bc][r0][q0] = pre0;
        *(float4*)&xs[bc][r1][q1] = pre1;
        if (tid < TJ) xd[bc][tid] = pred;
        __syncthreads();
        if (t + 1 < NT) {
            pre0 = gsrc[(t + 1)*512 + tid];
            pre1 = gsrc[(t + 1)*512 + tid + 256];
            if (tid < TJ) pred = dbh[(t + 1)*TJ + tid];
        }

        u64 wA = brA[t], wB = brB[t];

        float4 xj4[8];
#pragma unroll
        for (int q = 0; q < 8; ++q) xj4[q] = *(const float4*)&xs[bc][l][4*q];
        float dj = xd[bc][l];

        float sA0 = 0.f, sA1 = 0.f, sA2 = 0.f, sA3 = 0.f;
        float sB0 = 0.f, sB1 = 0.f, sB2 = 0.f, sB3 = 0.f;
#pragma unroll
        for (int q = 0; q < 8; ++q) {
            float4 xv = xj4[q];
            float v;
            v = xiA[4*q+0] + xv.x; sA0 = fmaf(wa4[4*q+0], fabsf(v), sA0);
            v = xiA[4*q+1] + xv.y; sA1 = fmaf(wa4[4*q+1], fabsf(v), sA1);
            v = xiA[4*q+2] + xv.z; sA2 = fmaf(wa4[4*q+2], fabsf(v), sA2);
            v = xiA[4*q+3] + xv.w; sA3 = fmaf(wa4[4*q+3], fabsf(v), sA3);
            v = xiB[4*q+0] + xv.x; sB0 = fmaf(wa4[4*q+0], fabsf(v), sB0);
            v = xiB[4*q+1] + xv.y; sB1 = fmaf(wa4[4*q+1], fabsf(v), sB1);
            v = xiB[4*q+2] + xv.z; sB2 = fmaf(wa4[4*q+2], fabsf(v), sB2);
            v = xiB[4*q+3] + xv.w; sB3 = fmaf(wa4[4*q+3], fabsf(v), sB3);
        }
        float eA = (ciA + dj) + ((sA0 + sA1) + (sA2 + sA3));
        float eB = (ciB + dj) + ((sB0 + sB1) + (sB2 + sB3));
        float pA = ((wA >> l) & 1ull) ? __expf(eA) : 0.f;   // fixed m=0
        float pB = ((wB >> l) & 1ull) ? __expf(eB) : 0.f;
        lsA += pA;
        lsB += pB;
#pragma unroll
        for (int q = 0; q < 8; ++q) {
            float4 xv = xj4[q];
            accA[4*q+0] = fmaf(pA, xv.x, accA[4*q+0]);
            accA[4*q+1] = fmaf(pA, xv.y, accA[4*q+1]);
            accA[4*q+2] = fmaf(pA, xv.z, accA[4*q+2]);
            accA[4*q+3] = fmaf(pA, xv.w, accA[4*q+3]);
            accB[4*q+0] = fmaf(pB, xv.x, accB[4*q+0]);
            accB[4*q+1] = fmaf(pB, xv.y, accB[4*q+1]);
            accB[4*q+2] = fmaf(pB, xv.z, accB[4*q+2]);
            accB[4*q+3] = fmaf(pB, xv.w, accB[4*q+3]);
        }
    }

    // ---- epilogue: fold upper 32 lanes into lower (j=32..63 partials!), then
    // denominators + per-wave 32x33 LDS transpose-reduce reusing xs as scratch.
#pragma unroll
    for (int k = 0; k < HID; ++k) {
        accA[k] += __shfl_xor(accA[k], 32, 64);
        accB[k] += __shfl_xor(accB[k], 32, 64);
    }
#pragma unroll
    for (int off = 32; off >= 1; off >>= 1) {
        lsA += __shfl_xor(lsA, off, 64);
        lsB += __shfl_xor(lsB, off, 64);
    }
    float invA = 1.0f / lsA, invB = 1.0f / lsB;
    float* orowA = out + ((size_t)(b*NN + iA))*(HH*HID) + h*HID;
    float* orowB = out + ((size_t)(b*NN + iB))*(HH*HID) + h*HID;

    __syncthreads();                       // all tile reads done; xs reusable
    float* sw = (float*)xs + w * (32*33);  // wave-private 4.2 KB region
    if (l < 32) {
#pragma unroll
        for (int k = 0; k < HID; ++k) sw[k*33 + l] = accA[k];
    }
    if (l < 32) {
        float res = 0.f;
#pragma unroll
        for (int m = 0; m < 32; ++m) res += sw[l*33 + m];
        orowA[l] = res * invA;
    }
    if (l < 32) {
#pragma unroll
        for (int k = 0; k < HID; ++k) sw[k*33 + l] = accB[k];
    }
    if (l < 32) {
        float res = 0.f;
#pragma unroll
        for (int m = 0; m < 32; ++m) res += sw[l*33 + m];
        orowB[l] = res * invB;
    }
}

extern "C" void kernel_launch(void* const* d_in, const int* in_sizes, int n_in,
                              void* d_out, int out_size, void* d_ws, size_t ws_size,
                              hipStream_t stream) {
    const float* node_feat = (const float*)d_in[0];
    const int*   adj_mtx   = (const int*)d_in[1];
    const float* W         = (const float*)d_in[2];
    const float* Wa        = (const float*)d_in[3];
    float* out = (float*)d_out;

    char* ws = (char*)d_ws;
    float* x_ws  = (float*)(ws + WS_X);
    float* d6_ws = (float*)(ws + WS_D6);
    u64*   bits  = (u64*)(ws + WS_BITS);

    hipLaunchKernelGGL(gat_proj_kernel, dim3(BB*NN/2), dim3(128), 0, stream,
                       node_feat, W, Wa, adj_mtx, x_ws, d6_ws, bits);
    hipLaunchKernelGGL(gat_attn2_kernel, dim3(BB*HH*NN/8), dim3(256), 0, stream,
                       x_ws, d6_ws, bits, Wa, out);
}

// Round 8
// 45.217 us; speedup vs baseline: 2.4988x; 1.1375x over previous
//
#include <hip/hip_runtime.h>
#include <math.h>

#define BB 2
#define NN 1024
#define HH 4
#define F_IN 128
#define HID 32
#define TJ 64
#define NT (NN/TJ)     // 16 j-tiles, one u64 mask word each

typedef unsigned long long u64;

// ---- workspace layout (bytes) ----
#define WS_X    0              // f32 x [bh][n][k]          = 1048576
#define WS_X4   1048576        // f32 planes [bh][q][n][4]  = 1048576
#define WS_D6   2097152        // f32 [bh][n]               = 32768
#define WS_BITS 2129920        // u64 [b][n][NT]            = 262144  (end 2392064)

// ---------------- Kernel 1: proj (x=feat@W) + plane copy + d6 + adjacency bit-pack
// R6-verbatim except the two x4 plane stores.
__global__ __launch_bounds__(128) void gat_proj_kernel(const float* __restrict__ feat,
        const float* __restrict__ W, const float* __restrict__ Wa, const int* __restrict__ adj,
        float* __restrict__ xout, float* __restrict__ x4, float* __restrict__ d6,
        u64* __restrict__ bits) {
    const int RPB = 2;
    int blk = blockIdx.x;              // 0 .. BB*NN/2-1
    int b  = blk / (NN / RPB);
    int n0 = (blk % (NN / RPB)) * RPB;
    int t  = threadIdx.x;              // 0..127 -> output column h*32+k

    __shared__ float fs[RPB][F_IN];
    fs[0][t] = feat[((size_t)(b*NN + n0    ))*F_IN + t];
    fs[1][t] = feat[((size_t)(b*NN + n0 + 1))*F_IN + t];
    __syncthreads();

    float a0 = 0.f, a1 = 0.f;
    for (int f = 0; f < F_IN; ++f) {
        float w = W[f*(HH*HID) + t];
        a0 = fmaf(fs[0][f], w, a0);
        a1 = fmaf(fs[1][f], w, a1);
    }
    int h = t >> 5, k = t & 31;
    int bh = b*HH + h;
    xout[((size_t)bh*NN + n0    )*HID + k] = a0;
    xout[((size_t)bh*NN + n0 + 1)*HID + k] = a1;
    // k-quad-major planes: float idx (bh*8 + k/4)*4096 + n*4 + k%4
    x4[((size_t)bh*8 + (k >> 2))*(NN*4) + (n0    )*4 + (k & 3)] = a0;
    x4[((size_t)bh*8 + (k >> 2))*(NN*4) + (n0 + 1)*4 + (k & 3)] = a1;

    float w_t = Wa[t];
    float p0 = a0*w_t, p1 = a1*w_t;
#pragma unroll
    for (int off = 16; off >= 1; off >>= 1) {
        p0 += __shfl_xor(p0, off, 32);
        p1 += __shfl_xor(p1, off, 32);
    }
    if (k == 0) {
        d6[(size_t)bh*NN + n0    ] = 0.6f*p0;
        d6[(size_t)bh*NN + n0 + 1] = 0.6f*p1;
    }
    // adjacency bit-pack for this block's 2 rows
#pragma unroll
    for (int r = 0; r < RPB; ++r) {
        const int* arow = adj + ((size_t)(b*NN + n0 + r))*NN;
        u64* brow = bits + ((size_t)(b*NN + n0 + r))*NT;
#pragma unroll
        for (int c0 = 0; c0 < NN; c0 += 128) {
            u64 m = __ballot(arow[c0 + t] > 0);
            if ((t & 63) == 0) brow[(c0 + t) >> 6] = m;
        }
    }
}

// ---------------- Kernel 2: fused attention. 256 thr (4 waves), 2 rows/wave, 8 rows/block.
// R6-verbatim compute core and epilogue; ONLY change: xj read directly from x4 planes
// (coalesced 1KB wave-loads), no LDS tiles, no barriers.
__global__ __launch_bounds__(256) void gat_attn3_kernel(const float* __restrict__ x,
                                                        const float4* __restrict__ x4,
                                                        const float* __restrict__ d6,
                                                        const u64* __restrict__ bits,
                                                        const float* __restrict__ Wa,
                                                        float* __restrict__ out) {
    const int tid = threadIdx.x;
    const int w = __builtin_amdgcn_readfirstlane(tid >> 6);   // wave id 0..3
    const int l = tid & 63;
    const int blk = blockIdx.x;                // 0..1023
    const int bh = blk >> 7;                   // 128 blocks per (b,h)
    const int i0 = (blk & 127) << 3;           // 8 rows per block
    const int h = bh & (HH - 1), b = bh >> 2;
    const int iA = i0 + 2*w, iB = iA + 1;

    const float* xbh = x  + (size_t)bh * NN * HID;
    const float* dbh = d6 + (size_t)bh * NN;
    const u64* brA = bits + ((size_t)b*NN + iA) * NT;
    const u64* brB = bits + ((size_t)b*NN + iB) * NT;
    const float4* xq = x4 + (size_t)bh * 8 * NN;   // 8 k-quad planes

    float xiA[HID], xiB[HID], wa4[HID];
#pragma unroll
    for (int k = 0; k < HID; ++k) {
        xiA[k] = xbh[(size_t)iA*HID + k];
        xiB[k] = xbh[(size_t)iB*HID + k];
        wa4[k] = 0.4f * Wa[h*HID + k];
    }
    float ciA = dbh[iA], ciB = dbh[iB];

    float accA[HID], accB[HID];
#pragma unroll
    for (int k = 0; k < HID; ++k) { accA[k] = 0.f; accB[k] = 0.f; }
    float lsA = 0.f, lsB = 0.f;

    for (int t = 0; t < NT; ++t) {
        const int j = t*TJ + l;
        float4 xj4[8];
#pragma unroll
        for (int q = 0; q < 8; ++q) xj4[q] = xq[q*NN + j];
        float dj = dbh[j];
        u64 wA = brA[t], wB = brB[t];

        // e = 0.6*(d_i+d_j) + sum_k 0.4*wa_k*|x_i+x_j|  (== wa . lrelu(x_i+x_j))
        float sA0 = 0.f, sA1 = 0.f, sA2 = 0.f, sA3 = 0.f;
        float sB0 = 0.f, sB1 = 0.f, sB2 = 0.f, sB3 = 0.f;
#pragma unroll
        for (int q = 0; q < 8; ++q) {
            float4 xv = xj4[q];
            float v;
            v = xiA[4*q+0] + xv.x; sA0 = fmaf(wa4[4*q+0], fabsf(v), sA0);
            v = xiA[4*q+1] + xv.y; sA1 = fmaf(wa4[4*q+1], fabsf(v), sA1);
            v = xiA[4*q+2] + xv.z; sA2 = fmaf(wa4[4*q+2], fabsf(v), sA2);
            v = xiA[4*q+3] + xv.w; sA3 = fmaf(wa4[4*q+3], fabsf(v), sA3);
            v = xiB[4*q+0] + xv.x; sB0 = fmaf(wa4[4*q+0], fabsf(v), sB0);
            v = xiB[4*q+1] + xv.y; sB1 = fmaf(wa4[4*q+1], fabsf(v), sB1);
            v = xiB[4*q+2] + xv.z; sB2 = fmaf(wa4[4*q+2], fabsf(v), sB2);
            v = xiB[4*q+3] + xv.w; sB3 = fmaf(wa4[4*q+3], fabsf(v), sB3);
        }
        float eA = (ciA + dj) + ((sA0 + sA1) + (sA2 + sA3));
        float eB = (ciB + dj) + ((sB0 + sB1) + (sB2 + sB3));
        float pA = ((wA >> l) & 1ull) ? __expf(eA) : 0.f;   // fixed m=0
        float pB = ((wB >> l) & 1ull) ? __expf(eB) : 0.f;
        lsA += pA;
        lsB += pB;
#pragma unroll
        for (int q = 0; q < 8; ++q) {
            float4 xv = xj4[q];
            accA[4*q+0] = fmaf(pA, xv.x, accA[4*q+0]);
            accA[4*q+1] = fmaf(pA, xv.y, accA[4*q+1]);
            accA[4*q+2] = fmaf(pA, xv.z, accA[4*q+2]);
            accA[4*q+3] = fmaf(pA, xv.w, accA[4*q+3]);
            accB[4*q+0] = fmaf(pB, xv.x, accB[4*q+0]);
            accB[4*q+1] = fmaf(pB, xv.y, accB[4*q+1]);
            accB[4*q+2] = fmaf(pB, xv.z, accB[4*q+2]);
            accB[4*q+3] = fmaf(pB, xv.w, accB[4*q+3]);
        }
    }

    // ---- epilogue (R6-verbatim): fold upper 32 lanes, reduce denominators,
    // per-wave 32x33 LDS transpose-reduce in a wave-private region (no barrier).
#pragma unroll
    for (int k = 0; k < HID; ++k) {
        accA[k] += __shfl_xor(accA[k], 32, 64);
        accB[k] += __shfl_xor(accB[k], 32, 64);
    }
#pragma unroll
    for (int off = 32; off >= 1; off >>= 1) {
        lsA += __shfl_xor(lsA, off, 64);
        lsB += __shfl_xor(lsB, off, 64);
    }
    float invA = 1.0f / lsA, invB = 1.0f / lsB;
    float* orowA = out + ((size_t)(b*NN + iA))*(HH*HID) + h*HID;
    float* orowB = out + ((size_t)(b*NN + iB))*(HH*HID) + h*HID;

    __shared__ float scr[4][32*33];        // 16.9 KB, wave-private regions
    float* sw = scr[w];
    if (l < 32) {
#pragma unroll
        for (int k = 0; k < HID; ++k) sw[k*33 + l] = accA[k];
    }
    if (l < 32) {
        float res = 0.f;
#pragma unroll
        for (int m = 0; m < 32; ++m) res += sw[l*33 + m];
        orowA[l] = res * invA;
    }
    if (l < 32) {
#pragma unroll
        for (int k = 0; k < HID; ++k) sw[k*33 + l] = accB[k];
    }
    if (l < 32) {
        float res = 0.f;
#pragma unroll
        for (int m = 0; m < 32; ++m) res += sw[l*33 + m];
        orowB[l] = res * invB;
    }
}

extern "C" void kernel_launch(void* const* d_in, const int* in_sizes, int n_in,
                              void* d_out, int out_size, void* d_ws, size_t ws_size,
                              hipStream_t stream) {
    const float* node_feat = (const float*)d_in[0];
    const int*   adj_mtx   = (const int*)d_in[1];
    const float* W         = (const float*)d_in[2];
    const float* Wa        = (const float*)d_in[3];
    float* out = (float*)d_out;

    char* ws = (char*)d_ws;
    float* x_ws  = (float*)(ws + WS_X);
    float* x4_ws = (float*)(ws + WS_X4);
    float* d6_ws = (float*)(ws + WS_D6);
    u64*   bits  = (u64*)(ws + WS_BITS);

    hipLaunchKernelGGL(gat_proj_kernel, dim3(BB*NN/2), dim3(128), 0, stream,
                       node_feat, W, Wa, adj_mtx, x_ws, x4_ws, d6_ws, bits);
    hipLaunchKernelGGL(gat_attn3_kernel, dim3(BB*HH*NN/8), dim3(256), 0, stream,
                       x_ws, (const float4*)x4_ws, d6_ws, bits, Wa, out);
}